// Round 7
// baseline (465.587 us; speedup 1.0000x reference)
//
#include <hip/hip_runtime.h>
#include <math.h>

#define N_NODES 40000
#define N_EDGES 640000
#define IN_F 256
#define H_F 128
#define C_F 64
#define L_LAYERS 4
#define SCAN_BLKS 157    // ceil(40000/256)
#define N_CHUNKS 32
#define CHUNK_E 20000    // N_EDGES / N_CHUNKS
#define LDS_STRIDE 132   // 128 + 4 pad: breaks 16-way bank conflict on MFMA-phase reads

typedef short short8 __attribute__((ext_vector_type(8)));
typedef unsigned short ushort8 __attribute__((ext_vector_type(8)));
typedef float f32x4 __attribute__((ext_vector_type(4)));

__device__ inline short to_bf16(float f) {
    unsigned u = __builtin_bit_cast(unsigned, f);
    unsigned r = (u + 0x7FFFu + ((u >> 16) & 1u)) >> 16;
    return (short)r;
}
__device__ inline float bf16_to_f(unsigned short u) {
    unsigned v = ((unsigned)u) << 16;
    return __builtin_bit_cast(float, v);
}

// 256-thread block exclusive scan; returns excl; *tot = block total
__device__ inline int block_excl_scan(int v, int* wsum, int* tot) {
    int tid = threadIdx.x;
    int lane = tid & 63, wid = tid >> 6;
    int incl = v;
    #pragma unroll
    for (int off = 1; off < 64; off <<= 1) {
        int t = __shfl_up(incl, off, 64);
        if (lane >= off) incl += t;
    }
    if (lane == 63) wsum[wid] = incl;
    __syncthreads();
    int prefix = 0, total = 0;
    #pragma unroll
    for (int w = 0; w < 4; w++) {
        int s = wsum[w];
        if (w < wid) prefix += s;
        total += s;
    }
    *tot = total;
    return prefix + incl - v;
}

// ---------------- weight prep: transpose + bf16 (WcatT pre-scaled by ALPHA=0.5) --
__global__ void prep_w(const float* __restrict__ fc1_w,
                       const float* __restrict__ W1, const float* __restrict__ W2,
                       const float* __restrict__ fc2_w,
                       short* __restrict__ fc1_wT, short* __restrict__ WcatT,
                       short* __restrict__ fc2_wT) {
    int i = blockIdx.x * 256 + threadIdx.x;
    if (i < 128 * 256) {
        int n = i >> 8, k = i & 255;
        fc1_wT[i] = to_bf16(fc1_w[k * H_F + n]);
    }
    if (i < 4 * 128 * 256) {
        int l = i >> 15; int r = i & 32767; int n = r >> 8; int k = r & 255;
        float w = (k < 128) ? W1[l * 16384 + k * H_F + n]
                            : W2[l * 16384 + (k - 128) * H_F + n];
        WcatT[i] = to_bf16(0.5f * w);
    }
    if (i < 64 * 128) {
        int n = i >> 7, k = i & 127;
        fc2_wT[i] = to_bf16(fc2_w[k * C_F + n]);
    }
}

#define CVT8(dstv, p) {                                                         \
    float4 _v0 = *(const float4*)(p); float4 _v1 = *(const float4*)((p) + 4);   \
    dstv[0] = to_bf16(_v0.x); dstv[1] = to_bf16(_v0.y);                         \
    dstv[2] = to_bf16(_v0.z); dstv[3] = to_bf16(_v0.w);                         \
    dstv[4] = to_bf16(_v1.x); dstv[5] = to_bf16(_v1.y);                         \
    dstv[6] = to_bf16(_v1.z); dstv[7] = to_bf16(_v1.w); }

// ---------------- K1: LDS-histogram chunks (no global atomics) || fc1 MFMA ------
// blocks [0,32): dst-chunk histogram + per-edge rank; [32,64): src-chunk counts;
// blocks [64,689): fc1 rows. Packed 2x16-bit counters per LDS int (node d ->
// word d>>1, half d&1; per-chunk counts ~Poisson(0.5) so no half overflow).
__global__ __launch_bounds__(256) void hist_fc1(const int* __restrict__ src,
                                                const int* __restrict__ dst,
                                                int* __restrict__ chunk_dst,
                                                int* __restrict__ chunk_src,
                                                unsigned char* __restrict__ lrank8,
                                                const float* __restrict__ x,
                                                const short* __restrict__ wT,
                                                const float* __restrict__ b,
                                                unsigned short* __restrict__ h0b) {
    __shared__ int cntp[CHUNK_E];   // 80 KB; also reserved (unused) by fc1 blocks
    int blk = blockIdx.x;
    if (blk < 64) {
        int role_dst = (blk < 32);
        int w = role_dst ? blk : blk - 32;
        const int* idx = role_dst ? dst : src;
        int base = w * CHUNK_E;
        for (int i = threadIdx.x; i < CHUNK_E; i += 256) cntp[i] = 0;
        __syncthreads();
        if (role_dst) {
            for (int i = threadIdx.x; i < CHUNK_E; i += 256) {
                int d = idx[base + i];
                int sh = (d & 1) * 16;
                int old = atomicAdd(&cntp[d >> 1], 1 << sh);
                lrank8[base + i] = (unsigned char)((old >> sh) & 0xffff);
            }
        } else {
            for (int i = threadIdx.x; i < CHUNK_E; i += 256) {
                int s = idx[base + i];
                atomicAdd(&cntp[s >> 1], 1 << ((s & 1) * 16));
            }
        }
        __syncthreads();
        int* outp = role_dst ? (chunk_dst + w * CHUNK_E) : (chunk_src + w * CHUNK_E);
        for (int i = threadIdx.x; i < CHUNK_E; i += 256) outp[i] = cntp[i];
        return;
    }
    // ---- fc1 role ----
    int bb = blk - 64;
    int tid = threadIdx.x;
    int wave = tid >> 6, lane = tid & 63;
    int m = lane & 15, quad = lane >> 4;
    int row = bb * 64 + wave * 16 + m;
    const float* xr = x + (size_t)row * IN_F + quad * 8;
    short8 afrag[8];
    #pragma unroll
    for (int ks = 0; ks < 8; ks++) {
        CVT8(afrag[ks], xr + ks * 32);
    }
    #pragma unroll
    for (int c = 0; c < 8; c += 2) {
        f32x4 acc0 = {0.f, 0.f, 0.f, 0.f};
        f32x4 acc1 = {0.f, 0.f, 0.f, 0.f};
        const short* b0p = wT + (size_t)(c * 16 + m) * IN_F + quad * 8;
        const short* b1p = b0p + 16 * IN_F;
        #pragma unroll
        for (int ks = 0; ks < 8; ks++) {
            short8 b0 = *(const short8*)(b0p + ks * 32);
            short8 b1 = *(const short8*)(b1p + ks * 32);
            acc0 = __builtin_amdgcn_mfma_f32_16x16x32_bf16(afrag[ks], b0, acc0, 0, 0, 0);
            acc1 = __builtin_amdgcn_mfma_f32_16x16x32_bf16(afrag[ks], b1, acc1, 0, 0, 0);
        }
        int col0 = c * 16 + m;
        int rbase = bb * 64 + wave * 16 + quad * 4;
        float bg0 = b[col0], bg1 = b[col0 + 16];
        #pragma unroll
        for (int r = 0; r < 4; r++) {
            size_t idx2 = (size_t)(rbase + r) * H_F + col0;
            float v0 = acc0[r] + bg0;
            float v1 = acc1[r] + bg1;
            v0 = v0 > 0.f ? v0 : 0.f;
            v1 = v1 > 0.f ? v1 : 0.f;
            h0b[idx2] = (unsigned short)to_bf16(v0);
            h0b[idx2 + 16] = (unsigned short)to_bf16(v1);
        }
    }
}

// ---------------- K2a: per-node chunk-prefix + degrees + block scan ----------
__global__ __launch_bounds__(256) void scan1(const int* __restrict__ chunk_dst,
                                             const int* __restrict__ chunk_src,
                                             unsigned short* __restrict__ base16,
                                             float* __restrict__ rsq_in,
                                             float* __restrict__ rsq_out,
                                             int* __restrict__ row_local,
                                             int* __restrict__ blk_sum) {
    __shared__ int wsum[4];
    int n = blockIdx.x * 256 + threadIdx.x;
    int deg_in = 0;
    if (n < N_NODES) {
        int word = n >> 1, sh = (n & 1) * 16;
        int run = 0;
        #pragma unroll 4
        for (int w = 0; w < N_CHUNKS; w++) {
            int v = (chunk_dst[w * CHUNK_E + word] >> sh) & 0xffff;
            base16[w * N_NODES + n] = (unsigned short)run;
            run += v;
        }
        deg_in = run;
        int so = 0;
        #pragma unroll 4
        for (int w = 0; w < N_CHUNKS; w++)
            so += (chunk_src[w * CHUNK_E + word] >> sh) & 0xffff;
        rsq_in[n] = 1.0f / sqrtf((float)(deg_in < 1 ? 1 : deg_in));
        rsq_out[n] = 1.0f / sqrtf((float)(so < 1 ? 1 : so));
    }
    int tot;
    int excl = block_excl_scan(deg_in, wsum, &tot);
    if (n < N_NODES) row_local[n] = excl;
    if (threadIdx.x == 0) blk_sum[blockIdx.x] = tot;
}

// ---------------- K2b: scan of block sums ----------------
__global__ __launch_bounds__(256) void scan2(const int* __restrict__ blk_sum,
                                             int* __restrict__ blk_off) {
    __shared__ int wsum[4];
    int t = threadIdx.x;
    int v = (t < SCAN_BLKS) ? blk_sum[t] : 0;
    int tot;
    int excl = block_excl_scan(v, wsum, &tot);
    if (t < SCAN_BLKS) blk_off[t] = excl;
}

// ---------------- K3: atomic-free CSR fill + row_ptr materialize --------------
__global__ __launch_bounds__(256) void fill_fused(const int* __restrict__ src,
                                                  const int* __restrict__ dst,
                                                  const unsigned char* __restrict__ lrank8,
                                                  const unsigned short* __restrict__ base16,
                                                  const int* __restrict__ row_local,
                                                  const int* __restrict__ blk_off,
                                                  const float* __restrict__ rsq_in,
                                                  const float* __restrict__ rsq_out,
                                                  int* __restrict__ col,
                                                  float* __restrict__ wv,
                                                  int* __restrict__ row_ptr) {
    int blk = blockIdx.x;
    if (blk < 2500) {
        int e = blk * 256 + threadIdx.x;
        int w = e / CHUNK_E;
        int s = src[e], d = dst[e];
        int rp = blk_off[d >> 8] + row_local[d] + (int)base16[w * N_NODES + d]
               + (int)lrank8[e];
        col[rp] = s;
        wv[rp] = rsq_out[s] * rsq_in[d];
        return;
    }
    int n = (blk - 2500) * 256 + threadIdx.x;
    if (n < N_NODES) row_ptr[n] = blk_off[n >> 8] + row_local[n];
    if (blk == 2500 && threadIdx.x == 0) row_ptr[N_NODES] = N_EDGES;
}

// ---------------- fused layer: SpMM (-> LDS) + GCN2 combine MFMA --------------
// Block = 64 nodes, 4 waves x 16 nodes. Phase 1: per-wave spmm into LDS tile
// (fp32, stride 132). Phase 2: MFMA A=[agg(bf16), h0b] with W pre-scaled 0.5,
// epilogue relu((1-b)*0.5*(agg+h0) + (feat@W1+f0@W2)*b + bgc + identity).
// identity == hb (the spmm input). Output bf16 only.
__global__ __launch_bounds__(256) void layer_fused(const unsigned short* __restrict__ hb,
                                                   const unsigned short* __restrict__ h0b,
                                                   const int* __restrict__ row_ptr,
                                                   const int* __restrict__ col,
                                                   const float* __restrict__ wv,
                                                   const short* __restrict__ wT,
                                                   const float* __restrict__ bgc,
                                                   float beta,
                                                   unsigned short* __restrict__ h_outb) {
    __shared__ float aggL[64 * LDS_STRIDE];
    int tid = threadIdx.x;
    int wave = tid >> 6, lane = tid & 63;
    int slot = lane >> 4, fi = lane & 15;
    int nodebase = blockIdx.x * 64 + wave * 16;

    // ---- phase 1: spmm for this wave's 16 nodes ----
    for (int i = 0; i < 16; i++) {
        int n = nodebase + i;
        int e0 = row_ptr[n], e1 = row_ptr[n + 1];
        float a[8] = {};
        int e = e0 + slot;
        for (; e + 12 < e1; e += 16) {
            int c0 = col[e];      float w0 = wv[e];
            int c1 = col[e + 4];  float w1 = wv[e + 4];
            int c2 = col[e + 8];  float w2 = wv[e + 8];
            int c3 = col[e + 12]; float w3 = wv[e + 12];
            ushort8 u0 = *(const ushort8*)(hb + (size_t)c0 * H_F + fi * 8);
            ushort8 u1 = *(const ushort8*)(hb + (size_t)c1 * H_F + fi * 8);
            ushort8 u2 = *(const ushort8*)(hb + (size_t)c2 * H_F + fi * 8);
            ushort8 u3 = *(const ushort8*)(hb + (size_t)c3 * H_F + fi * 8);
            #pragma unroll
            for (int j = 0; j < 8; j++) {
                a[j] += w0 * bf16_to_f(u0[j]) + w1 * bf16_to_f(u1[j])
                      + w2 * bf16_to_f(u2[j]) + w3 * bf16_to_f(u3[j]);
            }
        }
        for (; e < e1; e += 4) {
            int c = col[e];
            float w = wv[e];
            ushort8 u = *(const ushort8*)(hb + (size_t)c * H_F + fi * 8);
            #pragma unroll
            for (int j = 0; j < 8; j++) a[j] += w * bf16_to_f(u[j]);
        }
        #pragma unroll
        for (int mask = 16; mask <= 32; mask <<= 1) {
            #pragma unroll
            for (int j = 0; j < 8; j++) a[j] += __shfl_xor(a[j], mask, 64);
        }
        if (slot == 0) {
            float* ap = aggL + (wave * 16 + i) * LDS_STRIDE + fi * 8;
            float4 r0 = {a[0], a[1], a[2], a[3]};
            float4 r1 = {a[4], a[5], a[6], a[7]};
            *(float4*)ap = r0;
            *(float4*)(ap + 4) = r1;
        }
    }
    __syncthreads();

    // ---- phase 2: MFMA combine ----
    int m = lane & 15, quad = lane >> 4;
    const float* aggr = aggL + (wave * 16 + m) * LDS_STRIDE + quad * 8;
    const unsigned short* h0r = h0b + (size_t)(nodebase + m) * H_F + quad * 8;
    short8 afrag[8];
    #pragma unroll
    for (int ks = 0; ks < 4; ks++) {
        CVT8(afrag[ks], aggr + ks * 32);
    }
    #pragma unroll
    for (int ks = 0; ks < 4; ks++) {
        afrag[ks + 4] = __builtin_bit_cast(short8, *(const ushort8*)(h0r + ks * 32));
    }
    float omb = 1.f - beta;
    #pragma unroll
    for (int c = 0; c < 8; c += 2) {
        f32x4 acc0 = {0.f, 0.f, 0.f, 0.f};
        f32x4 acc1 = {0.f, 0.f, 0.f, 0.f};
        const short* b0p = wT + (size_t)(c * 16 + m) * 256 + quad * 8;
        const short* b1p = b0p + 16 * 256;
        #pragma unroll
        for (int ks = 0; ks < 8; ks++) {
            short8 b0 = *(const short8*)(b0p + ks * 32);
            short8 b1 = *(const short8*)(b1p + ks * 32);
            acc0 = __builtin_amdgcn_mfma_f32_16x16x32_bf16(afrag[ks], b0, acc0, 0, 0, 0);
            acc1 = __builtin_amdgcn_mfma_f32_16x16x32_bf16(afrag[ks], b1, acc1, 0, 0, 0);
        }
        int col0 = c * 16 + m;
        int rl = wave * 16 + quad * 4;
        #pragma unroll
        for (int r = 0; r < 4; r++) {
            size_t idx = (size_t)(nodebase + quad * 4 + r) * H_F + col0;
            float ag0 = aggL[(rl + r) * LDS_STRIDE + col0];
            float ag1 = aggL[(rl + r) * LDS_STRIDE + col0 + 16];
            float s0 = 0.5f * (ag0 + bf16_to_f(h0b[idx]));
            float s1 = 0.5f * (ag1 + bf16_to_f(h0b[idx + 16]));
            float v0 = omb * s0 + beta * acc0[r] + bgc[col0] + bf16_to_f(hb[idx]);
            float v1 = omb * s1 + beta * acc1[r] + bgc[col0 + 16] + bf16_to_f(hb[idx + 16]);
            v0 = v0 > 0.f ? v0 : 0.f;
            v1 = v1 > 0.f ? v1 : 0.f;
            h_outb[idx] = (unsigned short)to_bf16(v0);
            h_outb[idx + 16] = (unsigned short)to_bf16(v1);
        }
    }
}

// ---------------- fc2: out = h(bf16) @ fc2_w + b via bf16 MFMA ----------------
__global__ __launch_bounds__(256) void fc2_mfma(const unsigned short* __restrict__ hb,
                                                const short* __restrict__ wT,
                                                const float* __restrict__ b,
                                                float* __restrict__ out) {
    int tid = threadIdx.x;
    int wave = tid >> 6, lane = tid & 63;
    int m = lane & 15, quad = lane >> 4;
    int row = blockIdx.x * 64 + wave * 16 + m;
    const unsigned short* hr = hb + (size_t)row * H_F + quad * 8;
    short8 afrag[4];
    #pragma unroll
    for (int ks = 0; ks < 4; ks++) {
        afrag[ks] = __builtin_bit_cast(short8, *(const ushort8*)(hr + ks * 32));
    }
    #pragma unroll
    for (int c = 0; c < 4; c += 2) {
        f32x4 acc0 = {0.f, 0.f, 0.f, 0.f};
        f32x4 acc1 = {0.f, 0.f, 0.f, 0.f};
        const short* b0p = wT + (size_t)(c * 16 + m) * H_F + quad * 8;
        const short* b1p = b0p + 16 * H_F;
        #pragma unroll
        for (int ks = 0; ks < 4; ks++) {
            short8 b0 = *(const short8*)(b0p + ks * 32);
            short8 b1 = *(const short8*)(b1p + ks * 32);
            acc0 = __builtin_amdgcn_mfma_f32_16x16x32_bf16(afrag[ks], b0, acc0, 0, 0, 0);
            acc1 = __builtin_amdgcn_mfma_f32_16x16x32_bf16(afrag[ks], b1, acc1, 0, 0, 0);
        }
        int col0 = c * 16 + m;
        int rbase = blockIdx.x * 64 + wave * 16 + quad * 4;
        float bg0 = b[col0], bg1 = b[col0 + 16];
        #pragma unroll
        for (int r = 0; r < 4; r++) {
            size_t idx = (size_t)(rbase + r) * C_F + col0;
            out[idx] = acc0[r] + bg0;
            out[idx + 16] = acc1[r] + bg1;
        }
    }
}

extern "C" void kernel_launch(void* const* d_in, const int* in_sizes, int n_in,
                              void* d_out, int out_size, void* d_ws, size_t ws_size,
                              hipStream_t stream) {
    const float* x     = (const float*)d_in[0];
    const float* fc1_w = (const float*)d_in[1];
    const float* fc1_b = (const float*)d_in[2];
    const float* W1    = (const float*)d_in[3];
    const float* W2    = (const float*)d_in[4];
    const float* bgc   = (const float*)d_in[5];
    const float* fc2_w = (const float*)d_in[6];
    const float* fc2_b = (const float*)d_in[7];
    const int*   src   = (const int*)d_in[8];
    const int*   dst   = (const int*)d_in[9];
    float* out = (float*)d_out;

    char* p = (char*)d_ws;
    auto alloc = [&](size_t bytes) {
        char* r = p;
        p += (bytes + 255) & ~(size_t)255;
        return r;
    };
    int*   chunk_dst = (int*)alloc((size_t)N_CHUNKS * CHUNK_E * 4);
    int*   chunk_src = (int*)alloc((size_t)N_CHUNKS * CHUNK_E * 4);
    unsigned short* base16 = (unsigned short*)alloc((size_t)N_CHUNKS * N_NODES * 2);
    unsigned char*  lrank8 = (unsigned char*)alloc((size_t)N_EDGES);
    float* rsq_in  = (float*)alloc((size_t)N_NODES * 4);
    float* rsq_out = (float*)alloc((size_t)N_NODES * 4);
    int*   row_ptr   = (int*)alloc((size_t)(N_NODES + 1) * 4);
    int*   row_local = (int*)alloc((size_t)N_NODES * 4);
    int*   blk_sum   = (int*)alloc((size_t)SCAN_BLKS * 4);
    int*   blk_off   = (int*)alloc((size_t)SCAN_BLKS * 4);
    int*   col     = (int*)alloc((size_t)N_EDGES * 4);
    float* wv      = (float*)alloc((size_t)N_EDGES * 4);
    unsigned short* h0b = (unsigned short*)alloc((size_t)N_NODES * H_F * 2);
    unsigned short* hAb = (unsigned short*)alloc((size_t)N_NODES * H_F * 2);
    unsigned short* hBb = (unsigned short*)alloc((size_t)N_NODES * H_F * 2);
    short* fc1_wT  = (short*)alloc((size_t)128 * 256 * 2);
    short* WcatT   = (short*)alloc((size_t)4 * 128 * 256 * 2);
    short* fc2_wT  = (short*)alloc((size_t)64 * 128 * 2);

    prep_w<<<512, 256, 0, stream>>>(fc1_w, W1, W2, fc2_w, fc1_wT, WcatT, fc2_wT);
    hist_fc1<<<689, 256, 0, stream>>>(src, dst, chunk_dst, chunk_src, lrank8,
                                      x, fc1_wT, fc1_b, h0b);
    scan1<<<SCAN_BLKS, 256, 0, stream>>>(chunk_dst, chunk_src, base16,
                                         rsq_in, rsq_out, row_local, blk_sum);
    scan2<<<1, 256, 0, stream>>>(blk_sum, blk_off);
    fill_fused<<<2500 + SCAN_BLKS, 256, 0, stream>>>(src, dst, lrank8, base16,
                                                     row_local, blk_off, rsq_in, rsq_out,
                                                     col, wv, row_ptr);

    // all-bf16 layer chain: identity == spmm input buffer
    const unsigned short* sp_in[4] = {h0b, hAb, hBb, hAb};
    unsigned short* out_b[4]       = {hAb, hBb, hAb, hBb};
    for (int l = 0; l < L_LAYERS; l++) {
        float beta = (float)log(1.0 / (double)(l + 1) + 1.0);
        layer_fused<<<N_NODES / 64, 256, 0, stream>>>(sp_in[l], h0b, row_ptr, col, wv,
                                                      WcatT + (size_t)l * 128 * 256,
                                                      bgc + (size_t)l * H_F,
                                                      beta, out_b[l]);
    }
    fc2_mfma<<<N_NODES / 64, 256, 0, stream>>>(hBb, fc2_wT, fc2_b, out);
}

// Round 8
// 379.918 us; speedup vs baseline: 1.2255x; 1.2255x over previous
//
#include <hip/hip_runtime.h>
#include <math.h>

#define N_NODES 40000
#define N_EDGES 640000
#define IN_F 256
#define H_F 128
#define C_F 64
#define L_LAYERS 4
#define SCAN_BLKS 157    // ceil(40000/256)
#define N_CHUNKS 32
#define CHUNK_E 20000    // N_EDGES / N_CHUNKS
#define HIST_WORDS 10000 // N_NODES / 4 (4x8-bit packed counters per word)

typedef short short8 __attribute__((ext_vector_type(8)));
typedef unsigned short ushort8 __attribute__((ext_vector_type(8)));
typedef float f32x4 __attribute__((ext_vector_type(4)));

__device__ inline short to_bf16(float f) {
    unsigned u = __builtin_bit_cast(unsigned, f);
    unsigned r = (u + 0x7FFFu + ((u >> 16) & 1u)) >> 16;
    return (short)r;
}
__device__ inline float bf16_to_f(unsigned short u) {
    unsigned v = ((unsigned)u) << 16;
    return __builtin_bit_cast(float, v);
}

// 256-thread block exclusive scan; returns excl; *tot = block total
__device__ inline int block_excl_scan(int v, int* wsum, int* tot) {
    int tid = threadIdx.x;
    int lane = tid & 63, wid = tid >> 6;
    int incl = v;
    #pragma unroll
    for (int off = 1; off < 64; off <<= 1) {
        int t = __shfl_up(incl, off, 64);
        if (lane >= off) incl += t;
    }
    if (lane == 63) wsum[wid] = incl;
    __syncthreads();
    int prefix = 0, total = 0;
    #pragma unroll
    for (int w = 0; w < 4; w++) {
        int s = wsum[w];
        if (w < wid) prefix += s;
        total += s;
    }
    *tot = total;
    return prefix + incl - v;
}

// ---------------- weight prep: transpose + bf16 (WcatT pre-scaled by ALPHA=0.5) --
__global__ void prep_w(const float* __restrict__ fc1_w,
                       const float* __restrict__ W1, const float* __restrict__ W2,
                       const float* __restrict__ fc2_w,
                       short* __restrict__ fc1_wT, short* __restrict__ WcatT,
                       short* __restrict__ fc2_wT) {
    int i = blockIdx.x * 256 + threadIdx.x;
    if (i < 128 * 256) {
        int n = i >> 8, k = i & 255;
        fc1_wT[i] = to_bf16(fc1_w[k * H_F + n]);
    }
    if (i < 4 * 128 * 256) {
        int l = i >> 15; int r = i & 32767; int n = r >> 8; int k = r & 255;
        float w = (k < 128) ? W1[l * 16384 + k * H_F + n]
                            : W2[l * 16384 + (k - 128) * H_F + n];
        WcatT[i] = to_bf16(0.5f * w);
    }
    if (i < 64 * 128) {
        int n = i >> 7, k = i & 127;
        fc2_wT[i] = to_bf16(fc2_w[k * C_F + n]);
    }
}

#define CVT8(dstv, p) {                                                         \
    float4 _v0 = *(const float4*)(p); float4 _v1 = *(const float4*)((p) + 4);   \
    dstv[0] = to_bf16(_v0.x); dstv[1] = to_bf16(_v0.y);                         \
    dstv[2] = to_bf16(_v0.z); dstv[3] = to_bf16(_v0.w);                         \
    dstv[4] = to_bf16(_v1.x); dstv[5] = to_bf16(_v1.y);                         \
    dstv[6] = to_bf16(_v1.z); dstv[7] = to_bf16(_v1.w); }

// ---------------- K1: LDS-histogram chunks (no global atomics) || fc1 MFMA ------
// blocks [0,32): dst-chunk histogram + per-edge rank; [32,64): src-chunk counts;
// blocks [64,689): fc1 rows. 4x8-bit packed counters per LDS word (40 KB ->
// 4 blocks/CU so the fc1 role keeps decent occupancy). Per-chunk per-node
// count is ~Poisson(0.5), far below the 255 byte-counter limit.
__global__ __launch_bounds__(256) void hist_fc1(const int* __restrict__ src,
                                                const int* __restrict__ dst,
                                                int* __restrict__ chunk_dst,
                                                int* __restrict__ chunk_src,
                                                unsigned char* __restrict__ lrank8,
                                                const float* __restrict__ x,
                                                const short* __restrict__ wT,
                                                const float* __restrict__ b,
                                                unsigned short* __restrict__ h0b) {
    __shared__ int cntp[HIST_WORDS];   // 40 KB
    int blk = blockIdx.x;
    if (blk < 64) {
        int role_dst = (blk < 32);
        int w = role_dst ? blk : blk - 32;
        const int* idx = role_dst ? dst : src;
        int base = w * CHUNK_E;
        for (int i = threadIdx.x; i < HIST_WORDS; i += 256) cntp[i] = 0;
        __syncthreads();
        if (role_dst) {
            for (int i = threadIdx.x; i < CHUNK_E; i += 256) {
                int d = idx[base + i];
                int sh = (d & 3) * 8;
                int old = atomicAdd(&cntp[d >> 2], 1 << sh);
                lrank8[base + i] = (unsigned char)((old >> sh) & 0xff);
            }
        } else {
            for (int i = threadIdx.x; i < CHUNK_E; i += 256) {
                int s = idx[base + i];
                atomicAdd(&cntp[s >> 2], 1 << ((s & 3) * 8));
            }
        }
        __syncthreads();
        int* outp = role_dst ? (chunk_dst + w * HIST_WORDS) : (chunk_src + w * HIST_WORDS);
        for (int i = threadIdx.x; i < HIST_WORDS; i += 256) outp[i] = cntp[i];
        return;
    }
    // ---- fc1 role ----
    int bb = blk - 64;
    int tid = threadIdx.x;
    int wave = tid >> 6, lane = tid & 63;
    int m = lane & 15, quad = lane >> 4;
    int row = bb * 64 + wave * 16 + m;
    const float* xr = x + (size_t)row * IN_F + quad * 8;
    short8 afrag[8];
    #pragma unroll
    for (int ks = 0; ks < 8; ks++) {
        CVT8(afrag[ks], xr + ks * 32);
    }
    #pragma unroll
    for (int c = 0; c < 8; c += 2) {
        f32x4 acc0 = {0.f, 0.f, 0.f, 0.f};
        f32x4 acc1 = {0.f, 0.f, 0.f, 0.f};
        const short* b0p = wT + (size_t)(c * 16 + m) * IN_F + quad * 8;
        const short* b1p = b0p + 16 * IN_F;
        #pragma unroll
        for (int ks = 0; ks < 8; ks++) {
            short8 b0 = *(const short8*)(b0p + ks * 32);
            short8 b1 = *(const short8*)(b1p + ks * 32);
            acc0 = __builtin_amdgcn_mfma_f32_16x16x32_bf16(afrag[ks], b0, acc0, 0, 0, 0);
            acc1 = __builtin_amdgcn_mfma_f32_16x16x32_bf16(afrag[ks], b1, acc1, 0, 0, 0);
        }
        int col0 = c * 16 + m;
        int rbase = bb * 64 + wave * 16 + quad * 4;
        float bg0 = b[col0], bg1 = b[col0 + 16];
        #pragma unroll
        for (int r = 0; r < 4; r++) {
            size_t idx2 = (size_t)(rbase + r) * H_F + col0;
            float v0 = acc0[r] + bg0;
            float v1 = acc1[r] + bg1;
            v0 = v0 > 0.f ? v0 : 0.f;
            v1 = v1 > 0.f ? v1 : 0.f;
            h0b[idx2] = (unsigned short)to_bf16(v0);
            h0b[idx2 + 16] = (unsigned short)to_bf16(v1);
        }
    }
}

// ---------------- K2a: per-node chunk-prefix + degrees + block scan ----------
__global__ __launch_bounds__(256) void scan1(const int* __restrict__ chunk_dst,
                                             const int* __restrict__ chunk_src,
                                             unsigned short* __restrict__ base16,
                                             float* __restrict__ rsq_in,
                                             float* __restrict__ rsq_out,
                                             int* __restrict__ row_local,
                                             int* __restrict__ blk_sum) {
    __shared__ int wsum[4];
    int n = blockIdx.x * 256 + threadIdx.x;
    int deg_in = 0;
    if (n < N_NODES) {
        int word = n >> 2, sh = (n & 3) * 8;
        int run = 0;
        #pragma unroll 4
        for (int w = 0; w < N_CHUNKS; w++) {
            int v = (chunk_dst[w * HIST_WORDS + word] >> sh) & 0xff;
            base16[w * N_NODES + n] = (unsigned short)run;
            run += v;
        }
        deg_in = run;
        int so = 0;
        #pragma unroll 4
        for (int w = 0; w < N_CHUNKS; w++)
            so += (chunk_src[w * HIST_WORDS + word] >> sh) & 0xff;
        rsq_in[n] = 1.0f / sqrtf((float)(deg_in < 1 ? 1 : deg_in));
        rsq_out[n] = 1.0f / sqrtf((float)(so < 1 ? 1 : so));
    }
    int tot;
    int excl = block_excl_scan(deg_in, wsum, &tot);
    if (n < N_NODES) row_local[n] = excl;
    if (threadIdx.x == 0) blk_sum[blockIdx.x] = tot;
}

// ---------------- K2b: scan of block sums ----------------
__global__ __launch_bounds__(256) void scan2(const int* __restrict__ blk_sum,
                                             int* __restrict__ blk_off) {
    __shared__ int wsum[4];
    int t = threadIdx.x;
    int v = (t < SCAN_BLKS) ? blk_sum[t] : 0;
    int tot;
    int excl = block_excl_scan(v, wsum, &tot);
    if (t < SCAN_BLKS) blk_off[t] = excl;
}

// ---------------- K3: atomic-free CSR fill + row_ptr materialize --------------
__global__ __launch_bounds__(256) void fill_fused(const int* __restrict__ src,
                                                  const int* __restrict__ dst,
                                                  const unsigned char* __restrict__ lrank8,
                                                  const unsigned short* __restrict__ base16,
                                                  const int* __restrict__ row_local,
                                                  const int* __restrict__ blk_off,
                                                  const float* __restrict__ rsq_in,
                                                  const float* __restrict__ rsq_out,
                                                  int* __restrict__ col,
                                                  float* __restrict__ wv,
                                                  int* __restrict__ row_ptr) {
    int blk = blockIdx.x;
    if (blk < 2500) {
        int e = blk * 256 + threadIdx.x;
        int w = e / CHUNK_E;
        int s = src[e], d = dst[e];
        int rp = blk_off[d >> 8] + row_local[d] + (int)base16[w * N_NODES + d]
               + (int)lrank8[e];
        col[rp] = s;
        wv[rp] = rsq_out[s] * rsq_in[d];
        return;
    }
    int n = (blk - 2500) * 256 + threadIdx.x;
    if (n < N_NODES) row_ptr[n] = blk_off[n >> 8] + row_local[n];
    if (blk == 2500 && threadIdx.x == 0) row_ptr[N_NODES] = N_EDGES;
}

// ---------------- SpMM (bf16 h -> bf16 agg): one wave/node, 4 slots x 16 lanes -
__global__ __launch_bounds__(256) void spmm_kernel(const unsigned short* __restrict__ hb,
                                                   const int* __restrict__ row_ptr,
                                                   const int* __restrict__ col,
                                                   const float* __restrict__ wv,
                                                   unsigned short* __restrict__ aggb) {
    int wave = threadIdx.x >> 6, lane = threadIdx.x & 63;
    int slot = lane >> 4, fi = lane & 15;
    int n = blockIdx.x * 4 + wave;
    int e0 = row_ptr[n], e1 = row_ptr[n + 1];
    float a[8] = {};
    int e = e0 + slot;
    for (; e + 12 < e1; e += 16) {
        int c0 = col[e];      float w0 = wv[e];
        int c1 = col[e + 4];  float w1 = wv[e + 4];
        int c2 = col[e + 8];  float w2 = wv[e + 8];
        int c3 = col[e + 12]; float w3 = wv[e + 12];
        ushort8 u0 = *(const ushort8*)(hb + (size_t)c0 * H_F + fi * 8);
        ushort8 u1 = *(const ushort8*)(hb + (size_t)c1 * H_F + fi * 8);
        ushort8 u2 = *(const ushort8*)(hb + (size_t)c2 * H_F + fi * 8);
        ushort8 u3 = *(const ushort8*)(hb + (size_t)c3 * H_F + fi * 8);
        #pragma unroll
        for (int j = 0; j < 8; j++) {
            a[j] += w0 * bf16_to_f(u0[j]) + w1 * bf16_to_f(u1[j])
                  + w2 * bf16_to_f(u2[j]) + w3 * bf16_to_f(u3[j]);
        }
    }
    for (; e < e1; e += 4) {
        int c = col[e];
        float w = wv[e];
        ushort8 u = *(const ushort8*)(hb + (size_t)c * H_F + fi * 8);
        #pragma unroll
        for (int j = 0; j < 8; j++) a[j] += w * bf16_to_f(u[j]);
    }
    #pragma unroll
    for (int mask = 16; mask <= 32; mask <<= 1) {
        #pragma unroll
        for (int j = 0; j < 8; j++) a[j] += __shfl_xor(a[j], mask, 64);
    }
    if (slot == 0) {
        ushort8 r;
        #pragma unroll
        for (int j = 0; j < 8; j++) r[j] = (unsigned short)to_bf16(a[j]);
        *(ushort8*)(aggb + (size_t)n * H_F + fi * 8) = r;
    }
}

// ---------------- combine via bf16 MFMA (all-bf16 operands) -------------------
// A = [aggb, h0b] (direct bit-cast loads); W pre-scaled 0.5 => acc = feat@W1+f0@W2
// h_out = relu((1-b)*0.5*(agg+h0) + b*acc + bgc + identity(hb))
__global__ __launch_bounds__(256) void combine_mfma(const unsigned short* __restrict__ aggb,
                                                    const unsigned short* __restrict__ h0b,
                                                    const unsigned short* __restrict__ hb,
                                                    const short* __restrict__ wT,
                                                    const float* __restrict__ bgc,
                                                    float beta,
                                                    unsigned short* __restrict__ h_outb) {
    int tid = threadIdx.x;
    int wave = tid >> 6, lane = tid & 63;
    int m = lane & 15, quad = lane >> 4;
    int row = blockIdx.x * 64 + wave * 16 + m;
    const unsigned short* aggr = aggb + (size_t)row * H_F + quad * 8;
    const unsigned short* h0r  = h0b + (size_t)row * H_F + quad * 8;
    short8 afrag[8];
    #pragma unroll
    for (int ks = 0; ks < 4; ks++) {
        afrag[ks] = __builtin_bit_cast(short8, *(const ushort8*)(aggr + ks * 32));
        afrag[ks + 4] = __builtin_bit_cast(short8, *(const ushort8*)(h0r + ks * 32));
    }
    float omb = 1.f - beta;
    #pragma unroll
    for (int c = 0; c < 8; c += 2) {
        f32x4 acc0 = {0.f, 0.f, 0.f, 0.f};
        f32x4 acc1 = {0.f, 0.f, 0.f, 0.f};
        const short* b0p = wT + (size_t)(c * 16 + m) * 256 + quad * 8;
        const short* b1p = b0p + 16 * 256;
        #pragma unroll
        for (int ks = 0; ks < 8; ks++) {
            short8 b0 = *(const short8*)(b0p + ks * 32);
            short8 b1 = *(const short8*)(b1p + ks * 32);
            acc0 = __builtin_amdgcn_mfma_f32_16x16x32_bf16(afrag[ks], b0, acc0, 0, 0, 0);
            acc1 = __builtin_amdgcn_mfma_f32_16x16x32_bf16(afrag[ks], b1, acc1, 0, 0, 0);
        }
        int col0 = c * 16 + m;
        int rbase = blockIdx.x * 64 + wave * 16 + quad * 4;
        float bg0 = bgc[col0], bg1 = bgc[col0 + 16];
        #pragma unroll
        for (int r = 0; r < 4; r++) {
            size_t idx = (size_t)(rbase + r) * H_F + col0;
            float s0 = 0.5f * (bf16_to_f(aggb[idx]) + bf16_to_f(h0b[idx]));
            float s1 = 0.5f * (bf16_to_f(aggb[idx + 16]) + bf16_to_f(h0b[idx + 16]));
            float v0 = omb * s0 + beta * acc0[r] + bg0 + bf16_to_f(hb[idx]);
            float v1 = omb * s1 + beta * acc1[r] + bg1 + bf16_to_f(hb[idx + 16]);
            v0 = v0 > 0.f ? v0 : 0.f;
            v1 = v1 > 0.f ? v1 : 0.f;
            h_outb[idx] = (unsigned short)to_bf16(v0);
            h_outb[idx + 16] = (unsigned short)to_bf16(v1);
        }
    }
}

// ---------------- fc2: out = h(bf16) @ fc2_w + b via bf16 MFMA ----------------
__global__ __launch_bounds__(256) void fc2_mfma(const unsigned short* __restrict__ hb,
                                                const short* __restrict__ wT,
                                                const float* __restrict__ b,
                                                float* __restrict__ out) {
    int tid = threadIdx.x;
    int wave = tid >> 6, lane = tid & 63;
    int m = lane & 15, quad = lane >> 4;
    int row = blockIdx.x * 64 + wave * 16 + m;
    const unsigned short* hr = hb + (size_t)row * H_F + quad * 8;
    short8 afrag[4];
    #pragma unroll
    for (int ks = 0; ks < 4; ks++) {
        afrag[ks] = __builtin_bit_cast(short8, *(const ushort8*)(hr + ks * 32));
    }
    #pragma unroll
    for (int c = 0; c < 4; c += 2) {
        f32x4 acc0 = {0.f, 0.f, 0.f, 0.f};
        f32x4 acc1 = {0.f, 0.f, 0.f, 0.f};
        const short* b0p = wT + (size_t)(c * 16 + m) * H_F + quad * 8;
        const short* b1p = b0p + 16 * H_F;
        #pragma unroll
        for (int ks = 0; ks < 4; ks++) {
            short8 b0 = *(const short8*)(b0p + ks * 32);
            short8 b1 = *(const short8*)(b1p + ks * 32);
            acc0 = __builtin_amdgcn_mfma_f32_16x16x32_bf16(afrag[ks], b0, acc0, 0, 0, 0);
            acc1 = __builtin_amdgcn_mfma_f32_16x16x32_bf16(afrag[ks], b1, acc1, 0, 0, 0);
        }
        int col0 = c * 16 + m;
        int rbase = blockIdx.x * 64 + wave * 16 + quad * 4;
        float bg0 = b[col0], bg1 = b[col0 + 16];
        #pragma unroll
        for (int r = 0; r < 4; r++) {
            size_t idx = (size_t)(rbase + r) * C_F + col0;
            out[idx] = acc0[r] + bg0;
            out[idx + 16] = acc1[r] + bg1;
        }
    }
}

extern "C" void kernel_launch(void* const* d_in, const int* in_sizes, int n_in,
                              void* d_out, int out_size, void* d_ws, size_t ws_size,
                              hipStream_t stream) {
    const float* x     = (const float*)d_in[0];
    const float* fc1_w = (const float*)d_in[1];
    const float* fc1_b = (const float*)d_in[2];
    const float* W1    = (const float*)d_in[3];
    const float* W2    = (const float*)d_in[4];
    const float* bgc   = (const float*)d_in[5];
    const float* fc2_w = (const float*)d_in[6];
    const float* fc2_b = (const float*)d_in[7];
    const int*   src   = (const int*)d_in[8];
    const int*   dst   = (const int*)d_in[9];
    float* out = (float*)d_out;

    char* p = (char*)d_ws;
    auto alloc = [&](size_t bytes) {
        char* r = p;
        p += (bytes + 255) & ~(size_t)255;
        return r;
    };
    int*   chunk_dst = (int*)alloc((size_t)N_CHUNKS * HIST_WORDS * 4);
    int*   chunk_src = (int*)alloc((size_t)N_CHUNKS * HIST_WORDS * 4);
    unsigned short* base16 = (unsigned short*)alloc((size_t)N_CHUNKS * N_NODES * 2);
    unsigned char*  lrank8 = (unsigned char*)alloc((size_t)N_EDGES);
    float* rsq_in  = (float*)alloc((size_t)N_NODES * 4);
    float* rsq_out = (float*)alloc((size_t)N_NODES * 4);
    int*   row_ptr   = (int*)alloc((size_t)(N_NODES + 1) * 4);
    int*   row_local = (int*)alloc((size_t)N_NODES * 4);
    int*   blk_sum   = (int*)alloc((size_t)SCAN_BLKS * 4);
    int*   blk_off   = (int*)alloc((size_t)SCAN_BLKS * 4);
    int*   col     = (int*)alloc((size_t)N_EDGES * 4);
    float* wv      = (float*)alloc((size_t)N_EDGES * 4);
    unsigned short* aggb = (unsigned short*)alloc((size_t)N_NODES * H_F * 2);
    unsigned short* h0b  = (unsigned short*)alloc((size_t)N_NODES * H_F * 2);
    unsigned short* hAb  = (unsigned short*)alloc((size_t)N_NODES * H_F * 2);
    unsigned short* hBb  = (unsigned short*)alloc((size_t)N_NODES * H_F * 2);
    short* fc1_wT  = (short*)alloc((size_t)128 * 256 * 2);
    short* WcatT   = (short*)alloc((size_t)4 * 128 * 256 * 2);
    short* fc2_wT  = (short*)alloc((size_t)64 * 128 * 2);

    prep_w<<<512, 256, 0, stream>>>(fc1_w, W1, W2, fc2_w, fc1_wT, WcatT, fc2_wT);
    hist_fc1<<<689, 256, 0, stream>>>(src, dst, chunk_dst, chunk_src, lrank8,
                                      x, fc1_wT, fc1_b, h0b);
    scan1<<<SCAN_BLKS, 256, 0, stream>>>(chunk_dst, chunk_src, base16,
                                         rsq_in, rsq_out, row_local, blk_sum);
    scan2<<<1, 256, 0, stream>>>(blk_sum, blk_off);
    fill_fused<<<2500 + SCAN_BLKS, 256, 0, stream>>>(src, dst, lrank8, base16,
                                                     row_local, blk_off, rsq_in, rsq_out,
                                                     col, wv, row_ptr);

    // all-bf16 layer chain: identity == spmm input buffer
    const unsigned short* sp_in[4] = {h0b, hAb, hBb, hAb};
    unsigned short* out_b[4]       = {hAb, hBb, hAb, hBb};
    for (int l = 0; l < L_LAYERS; l++) {
        float beta = (float)log(1.0 / (double)(l + 1) + 1.0);
        spmm_kernel<<<N_NODES / 4, 256, 0, stream>>>(sp_in[l], row_ptr, col, wv, aggb);
        combine_mfma<<<N_NODES / 64, 256, 0, stream>>>(aggb, h0b, sp_in[l],
                                                       WcatT + (size_t)l * 128 * 256,
                                                       bgc + (size_t)l * H_F,
                                                       beta, out_b[l]);
    }
    fc2_mfma<<<N_NODES / 64, 256, 0, stream>>>(hBb, fc2_wT, fc2_b, out);
}